// Round 8
// baseline (286.202 us; speedup 1.0000x reference)
//
#include <hip/hip_runtime.h>
#include <math.h>

// Problem constants: B=64, MAX_H=64, MAX_W=32, D=512, S=8, HID=64
#define NB    64
#define MAXH  64
#define MAXW  32
#define DCH   512
#define SS    8
#define HID   64

#define QTOTAL ((size_t)NB * MAXH * MAXW * DCH)   // 67,108,864 floats

typedef float f4  __attribute__((ext_vector_type(4)));
typedef short s8v __attribute__((ext_vector_type(8)));   // 8 bf16 (4 VGPRs)

__device__ __forceinline__ float gelu_exact(float x) {
    // jax.nn.gelu(approximate=False): x * 0.5 * (1 + erf(x/sqrt(2)))
    return 0.5f * x * (1.0f + erff(x * 0.70710678118654752440f));
}

__device__ __forceinline__ unsigned short bf16_rne(float x) {
    unsigned int u = __float_as_uint(x);
    unsigned int r = u + 0x7fffu + ((u >> 16) & 1u);
    return (unsigned short)(r >> 16);
}

// ---------------------------------------------------------------------------
// Single persistent-style kernel. Grid 1024 x 256; block bx processes tiles
// raw = it*1024 + bx, it = 0..7, through the bijective swizzle
// id = raw ^ (raw>>7)  ->  (b, i, half). Each tile = 16 j x 512 c.
// Per wave, w2 B-fragments (16x16x32 bf16 MFMA: lane l holds
// B[k=(l>>4)*8+j][n=l&15]) are built ONCE into registers from f32 w2 and
// reused for all 8 tiles. Delta = 2 MFMAs; bilinear+b2 seeds the C fragment.
// ---------------------------------------------------------------------------
__global__ __launch_bounds__(256) void hgqg_kernel(
    const float* __restrict__ canonical,  // (8,8,512)
    const float* __restrict__ w1,         // (2,64)
    const float* __restrict__ b1,         // (64,)
    const float* __restrict__ w2,         // (64,512)
    const float* __restrict__ b2,         // (512,)
    const int*   __restrict__ hlist,      // (64,)
    const int*   __restrict__ wlist,      // (64,)
    float* __restrict__ out)              // queries flat, then mask flat
{
    const int t = threadIdx.x;
    const int l = t & 63;          // lane
    const int w = t >> 6;          // wave 0..3 -> channels [w*128, w*128+128)
    const int q = l >> 4;          // quad
    const int m = l & 15;          // lane-in-quad

    // ---- one-time per wave: w2 B-fragments + b2, into registers ----
    s8v  wfrag[16];                // [tt*2 + kh]
    float bb2[8];
    #pragma unroll
    for (int tt = 0; tt < 8; ++tt) {
        const int ct = w * 8 + tt;
        const int c  = ct * 16 + m;
        bb2[tt] = b2[c];
        #pragma unroll
        for (int kh = 0; kh < 2; ++kh) {
            union { s8v v; unsigned short us[8]; } pk;
            #pragma unroll
            for (int j = 0; j < 8; ++j) {
                const int k = kh * 32 + q * 8 + j;
                pk.us[j] = bf16_rne(w2[k * DCH + c]);
            }
            wfrag[tt * 2 + kh] = pk.v;
        }
    }

    __shared__ __align__(16) float ri[SS * 516];     // y-lerped rows, padded
    __shared__ __align__(16) float hsh[16][68];      // gelu MLP hidden

    const f4 z = {0.f, 0.f, 0.f, 0.f};

    #pragma unroll 1
    for (int it = 0; it < 8; ++it) {
        const int raw  = (it << 10) | blockIdx.x;    // 0..8191, unique
        const int id   = (raw ^ (raw >> 7)) & 8191;
        const int i    = id & 63;
        const int half = (id >> 6) & 1;
        const int b    = id >> 7;
        const int blk  = (b << 6) | i;

        int H = hlist[b]; H = min(max(H, 1), MAXH);
        int W = wlist[b]; W = min(max(W, 1), MAXW);
        const int jbase = half << 4;                 // 0 or 16

        f4* q4 = (f4*)(out + (size_t)blk * (MAXW * DCH)) + jbase * 128;

        if (half == 0 && t < MAXW) {
            out[QTOTAL + (size_t)blk * MAXW + t] = (i < H && t < W) ? 1.0f : 0.0f;
        }

        // Block-uniform branch (i, H, jbase, W uniform): no barrier divergence.
        if (i >= H || jbase >= W) {
            #pragma unroll
            for (int r = 0; r < 8; ++r) q4[t + r * 256] = z;
            continue;
        }

        // ---- per-row uniforms ----
        const float u    = (H > 1) ? (float)i / (float)(H - 1) : 0.0f;
        const float sy   = fminf(u * 7.0f, 7.0f);
        const int   y0   = (int)sy;
        const int   y1   = min(y0 + 1, SS - 1);
        const float wy   = sy - (float)y0;
        const float winv = (W > 1) ? 1.0f / (float)(W - 1) : 0.0f;

        __syncthreads();   // previous tile's LDS readers are done
        {
            // stage A: y-lerped canonical rows -> LDS (f32, stride 516)
            const f4* can4 = (const f4*)canonical;
            #pragma unroll
            for (int rr = 0; rr < 4; ++rr) {
                const int idx2 = t + rr * 256;       // 0..1023
                const int x    = idx2 >> 7;
                const int c4   = idx2 & 127;
                const f4 a = can4[(y0 * SS + x) * 128 + c4];
                const f4 d = can4[(y1 * SS + x) * 128 + c4];
                *(f4*)&ri[x * 516 + c4 * 4] = a + wy * (d - a);
            }
            // stage B: hsh[jl][k] = gelu(u*w1[0][k] + v*w1[1][k] + b1[k])
            const int jl = t >> 4;              // 0..15
            const int k0 = (t & 15) * 4;        // 0..60
            const float v = (float)(jbase + jl) * winv;
            #pragma unroll
            for (int kk = 0; kk < 4; ++kk) {
                const int k = k0 + kk;
                hsh[jl][k] = gelu_exact(u * w1[k] + v * w1[HID + k] + b1[k]);
            }
        }
        __syncthreads();

        // A-fragments (h): lane holds A[m][k=q*8+j] = hsh[m][q*8+j]
        union { s8v v; unsigned short us[8]; } A0, A1;
        {
            const float* hrow = &hsh[m][q * 8];
            #pragma unroll
            for (int j = 0; j < 8; ++j) {
                A0.us[j] = bf16_rne(hrow[j]);
                A1.us[j] = bf16_rne(hrow[32 + j]);
            }
        }

        // per-reg bilinear x-weights: C/D row = q*4 + r -> j = jbase + q*4 + r
        int   x0a[4], x1a[4];
        float wxa[4];
        #pragma unroll
        for (int r = 0; r < 4; ++r) {
            const int   j  = jbase + q * 4 + r;
            const float v  = (float)j * winv;
            const float sx = fminf(v * 7.0f, 7.0f);
            const int   x0 = (int)sx;
            x0a[r] = x0;
            x1a[r] = min(x0 + 1, SS - 1);
            wxa[r] = sx - (float)x0;
        }

        const bool fullhalf = (jbase + 16 <= W);   // wave-uniform
        const size_t obase = (size_t)blk * (MAXW * DCH) + (size_t)jbase * DCH;

        #pragma unroll
        for (int tt = 0; tt < 8; ++tt) {
            const int c = (w * 8 + tt) * 16 + m;   // this lane's channel

            // seed C with bilinear + b2 (C layout: row = q*4+r, col = m)
            f4 acc;
            #pragma unroll
            for (int r = 0; r < 4; ++r) {
                const float f0 = ri[x0a[r] * 516 + c];
                const float f1 = ri[x1a[r] * 516 + c];
                acc[r] = f0 + wxa[r] * (f1 - f0) + bb2[tt];
            }

            // delta: two chained K=32 MFMAs, B from registers
            acc = __builtin_amdgcn_mfma_f32_16x16x32_bf16(A0.v, wfrag[tt * 2 + 0], acc, 0, 0, 0);
            acc = __builtin_amdgcn_mfma_f32_16x16x32_bf16(A1.v, wfrag[tt * 2 + 1], acc, 0, 0, 0);

            // store; mask only boundary halves
            if (fullhalf) {
                #pragma unroll
                for (int r = 0; r < 4; ++r)
                    out[obase + (size_t)(q * 4 + r) * DCH + c] = acc[r];
            } else {
                #pragma unroll
                for (int r = 0; r < 4; ++r) {
                    const int j = jbase + q * 4 + r;
                    out[obase + (size_t)(q * 4 + r) * DCH + c] = (j < W) ? acc[r] : 0.0f;
                }
            }
        }
    }
}

extern "C" void kernel_launch(void* const* d_in, const int* in_sizes, int n_in,
                              void* d_out, int out_size, void* d_ws, size_t ws_size,
                              hipStream_t stream) {
    const float* canonical = (const float*)d_in[0];
    const float* w1        = (const float*)d_in[1];
    const float* b1        = (const float*)d_in[2];
    const float* w2        = (const float*)d_in[3];
    const float* b2        = (const float*)d_in[4];
    const int*   hlist     = (const int*)d_in[6];
    const int*   wlist     = (const int*)d_in[7];
    float* out = (float*)d_out;

    hgqg_kernel<<<1024, 256, 0, stream>>>(
        canonical, w1, b1, w2, b2, hlist, wlist, out);
}